// Round 1
// baseline (823.478 us; speedup 1.0000x reference)
//
#include <hip/hip_runtime.h>

#define E_TOT   100000
#define N_NODES 10000
#define DIMV    80
#define HID     64
#define EDIM    32
#define WNUM    2304
#define TE      32
#define TJ      128

static constexpr float NORMF      = 0.14433756729740643f;  // 1/sqrt(48)
static constexpr float INV_SQRT3F = 0.57735026918962576f;
static constexpr float RS32       = 0.17677669529663687f;  // 1/sqrt(32)
static constexpr float RS16       = 0.25f;                 // 1/sqrt(16)

// Edge kernel: per block of TE=32 edges:
//   H = relu(ea @ W1 + b1)            (32 x 64, in LDS transposed)
//   loop 18 j-tiles of 128: w_tile = H @ W2[:,tile] (+b2), staged via LDS,
//   contract on the fly into per-thread register partials:
//     pA[w'] += sh0*x0[u]*w   (wa tiles 0..7)   + xs1n[u]*w (wb tiles 14..17)
//     sC[w'] += x0[u]*w       (wc tiles 8..11)
//     sD[w'][m] += x1[u][m]*w (wd tiles 12..13)
//   msg[w']        = NORM*(pA)                       (out0, sh0/inv3 folded)
//   msg[32+3w'+m]  = NORM*(sh1[m]*sC + sh0*sD[m])    (out1)
//   then atomicAdd into sums[dst], cnt[dst].
__global__ __launch_bounds__(256) void edge_kernel(
    const int* __restrict__ dst, const float* __restrict__ x_src,
    const float* __restrict__ sh, const float* __restrict__ ea,
    const float* __restrict__ W1, const float* __restrict__ b1,
    const float* __restrict__ W2, const float* __restrict__ b2,
    float* __restrict__ sums, float* __restrict__ cnt)
{
    __shared__ float sX[TE][DIMV];    // x_src tile (x0 = [0:32), x1[u][m] = [32+3u+m])
    __shared__ float sSh[TE][4];
    __shared__ float sXs1[TE][16];    // INV_SQRT3 * sum_m x1[u][m]*sh1[m]
    __shared__ float sHt[HID][TE];    // H transposed [t][e]
    __shared__ float sW2[HID][TJ];    // current W2 tile
    __shared__ float sMsg[TE][DIMV];  // per-edge message accumulator (reused as ea temp)
    __shared__ int   sDst[TE];

    const int tid = threadIdx.x;
    const int e0  = blockIdx.x * TE;

    float* sEa = &sMsg[0][0];         // 32*32 = 1024 floats, fits in sMsg (2560)

    for (int i = tid; i < TE*DIMV; i += 256) sX[0][i]  = x_src[e0*DIMV + i];
    for (int i = tid; i < TE*EDIM; i += 256) sEa[i]    = ea[e0*EDIM + i];
    for (int i = tid; i < TE*4;    i += 256) sSh[0][i] = sh[e0*4 + i];
    if (tid < TE) sDst[tid] = dst[e0 + tid];
    __syncthreads();

    // H = relu(ea @ W1 + b1), 32x64 values, 8 per thread
    #pragma unroll
    for (int k = 0; k < (TE*HID)/256; ++k) {
        int idx = tid + k*256;
        int e = idx >> 6, t = idx & 63;
        float h = b1[t];
        #pragma unroll
        for (int i = 0; i < EDIM; ++i) h = fmaf(sEa[e*EDIM + i], W1[i*HID + t], h);
        sHt[t][e] = fmaxf(h, 0.f);
    }
    // xs1n
    for (int i = tid; i < TE*16; i += 256) {
        int e = i >> 4, u = i & 15;
        float s = 0.f;
        #pragma unroll
        for (int m = 0; m < 3; ++m) s = fmaf(sX[e][32 + u*3 + m], sSh[e][1+m], s);
        sXs1[0][i] = s * INV_SQRT3F;
    }
    __syncthreads();
    for (int i = tid; i < TE*DIMV; i += 256) sMsg[0][i] = 0.f;
    // (tile-0 stage() barrier makes zeros visible before any later use)

    const int jg  = tid & 31, eg = tid >> 5;
    const int e0l = eg << 2, jc0 = jg << 2;

    float pA[4][4]    = {};
    float sC[4][4]    = {};
    float sD[4][4][3] = {};

    auto stage = [&](int tile) {
        __syncthreads();
        const float* src = W2 + tile*TJ;
        #pragma unroll
        for (int k = 0; k < (HID*TJ/4)/256; ++k) {
            int i = tid + k*256;
            int t = i >> 5, c4 = (i & 31) << 2;
            *(float4*)&sW2[t][c4] = *(const float4*)&src[t*WNUM + c4];
        }
        __syncthreads();
    };
    auto gemm = [&](float (&acc)[4][4]) {
        #pragma unroll
        for (int a = 0; a < 4; ++a)
            #pragma unroll
            for (int b = 0; b < 4; ++b) acc[a][b] = 0.f;
        #pragma unroll 8
        for (int t = 0; t < HID; ++t) {
            float4 hv = *(float4*)&sHt[t][e0l];
            float4 wv = *(float4*)&sW2[t][jc0];
            float hh[4] = {hv.x, hv.y, hv.z, hv.w};
            float ww[4] = {wv.x, wv.y, wv.z, wv.w};
            #pragma unroll
            for (int a = 0; a < 4; ++a)
                #pragma unroll
                for (int b = 0; b < 4; ++b) acc[a][b] = fmaf(hh[a], ww[b], acc[a][b]);
        }
    };

    // ---- wa tiles: j in [0,1024), j = u*32 + w'
    for (int tile = 0; tile < 8; ++tile) {
        stage(tile);
        float acc[4][4]; gemm(acc);
        float4 bv = *(const float4*)&b2[tile*TJ + jc0];
        float bb[4] = {bv.x, bv.y, bv.z, bv.w};
        int u = (tile << 2) + (jg >> 3);
        #pragma unroll
        for (int re = 0; re < 4; ++re) {
            int e = e0l + re;
            float ca = sSh[e][0] * sX[e][u];
            #pragma unroll
            for (int c = 0; c < 4; ++c) pA[re][c] = fmaf(ca, acc[re][c] + bb[c], pA[re][c]);
        }
    }
    // ---- wc tiles: j in [1024,1536), j-1024 = u*16 + w'
    for (int tile = 8; tile < 12; ++tile) {
        stage(tile);
        float acc[4][4]; gemm(acc);
        float4 bv = *(const float4*)&b2[tile*TJ + jc0];
        float bb[4] = {bv.x, bv.y, bv.z, bv.w};
        int u = ((tile - 8) << 3) + (jg >> 2);
        #pragma unroll
        for (int re = 0; re < 4; ++re) {
            int e = e0l + re;
            float cc = sX[e][u];
            #pragma unroll
            for (int c = 0; c < 4; ++c) sC[re][c] = fmaf(cc, acc[re][c] + bb[c], sC[re][c]);
        }
    }
    // ---- wd tiles: j in [1536,1792), j-1536 = u*16 + w'
    for (int tile = 12; tile < 14; ++tile) {
        stage(tile);
        float acc[4][4]; gemm(acc);
        float4 bv = *(const float4*)&b2[tile*TJ + jc0];
        float bb[4] = {bv.x, bv.y, bv.z, bv.w};
        int u = ((tile - 12) << 3) + (jg >> 2);
        #pragma unroll
        for (int re = 0; re < 4; ++re) {
            int e = e0l + re;
            float c0 = sX[e][32 + u*3 + 0];
            float c1 = sX[e][32 + u*3 + 1];
            float c2 = sX[e][32 + u*3 + 2];
            #pragma unroll
            for (int c = 0; c < 4; ++c) {
                float wv2 = acc[re][c] + bb[c];
                sD[re][c][0] = fmaf(c0, wv2, sD[re][c][0]);
                sD[re][c][1] = fmaf(c1, wv2, sD[re][c][1]);
                sD[re][c][2] = fmaf(c2, wv2, sD[re][c][2]);
            }
        }
    }
    // ---- wb tiles: j in [1792,2304), j-1792 = u*32 + w'
    for (int tile = 14; tile < 18; ++tile) {
        stage(tile);
        float acc[4][4]; gemm(acc);
        float4 bv = *(const float4*)&b2[tile*TJ + jc0];
        float bb[4] = {bv.x, bv.y, bv.z, bv.w};
        int u = ((tile - 14) << 2) + (jg >> 3);
        #pragma unroll
        for (int re = 0; re < 4; ++re) {
            int e = e0l + re;
            float cb = sXs1[e][u];
            #pragma unroll
            for (int c = 0; c < 4; ++c) pA[re][c] = fmaf(cb, acc[re][c] + bb[c], pA[re][c]);
        }
    }

    __syncthreads();
    // reduce register partials into per-edge msg (LDS atomics; <=8-way contention)
    const int wA = (jg & 7) << 2;
    const int wC = (jg & 3) << 2;
    #pragma unroll
    for (int re = 0; re < 4; ++re) {
        int e = e0l + re;
        float s0 = sSh[e][0], s1 = sSh[e][1], s2 = sSh[e][2], s3 = sSh[e][3];
        #pragma unroll
        for (int c = 0; c < 4; ++c) {
            atomicAdd(&sMsg[e][wA + c], pA[re][c]);
            int kb = 32 + (wC + c)*3;
            atomicAdd(&sMsg[e][kb + 0], s1*sC[re][c] + s0*sD[re][c][0]);
            atomicAdd(&sMsg[e][kb + 1], s2*sC[re][c] + s0*sD[re][c][1]);
            atomicAdd(&sMsg[e][kb + 2], s3*sC[re][c] + s0*sD[re][c][2]);
        }
    }
    __syncthreads();
    // scatter to node sums (fold NORM here)
    for (int i = tid; i < TE*DIMV; i += 256) {
        int e = i / DIMV, k = i - e*DIMV;
        atomicAdd(&sums[sDst[e]*DIMV + k], NORMF * sMsg[0][i]);
    }
    if (tid < TE) atomicAdd(&cnt[sDst[tid]], 1.0f);
}

// Node kernel: out = residual + sums/max(cnt,1)
__global__ __launch_bounds__(256) void node_kernel(
    const float* __restrict__ x_dst, const float* __restrict__ rw0,
    const float* __restrict__ rw1, const float* __restrict__ sums,
    const float* __restrict__ cnt, float* __restrict__ out)
{
    int gid = blockIdx.x*256 + threadIdx.x;
    if (gid >= N_NODES*DIMV) return;
    int n = gid / DIMV;
    int k = gid - n*DIMV;
    const float* xd = x_dst + n*DIMV;
    float r = 0.f;
    if (k < 32) {
        #pragma unroll
        for (int u = 0; u < 32; ++u) r = fmaf(xd[u], rw0[u*32 + k], r);
        r *= RS32;
    } else {
        int kk = k - 32;
        int w = kk / 3, m = kk - w*3;
        #pragma unroll
        for (int u = 0; u < 16; ++u) r = fmaf(xd[32 + u*3 + m], rw1[u*16 + w], r);
        r *= RS16;
    }
    float c = cnt[n];
    out[gid] = r + sums[gid] / fmaxf(c, 1.f);
}

extern "C" void kernel_launch(void* const* d_in, const int* in_sizes, int n_in,
                              void* d_out, int out_size, void* d_ws, size_t ws_size,
                              hipStream_t stream) {
    const int*   dst   = (const int*)  d_in[0];
    const float* x_src = (const float*)d_in[1];
    const float* x_dst = (const float*)d_in[2];
    const float* sh    = (const float*)d_in[3];
    const float* ea    = (const float*)d_in[4];
    const float* W1    = (const float*)d_in[5];
    const float* b1    = (const float*)d_in[6];
    const float* W2    = (const float*)d_in[7];
    const float* b2    = (const float*)d_in[8];
    const float* rw0   = (const float*)d_in[9];
    const float* rw1   = (const float*)d_in[10];
    float* out  = (float*)d_out;
    float* sums = (float*)d_ws;
    float* cnt  = sums + (size_t)N_NODES*DIMV;

    hipMemsetAsync(d_ws, 0, (size_t)(N_NODES*DIMV + N_NODES)*sizeof(float), stream);
    edge_kernel<<<E_TOT/TE, 256, 0, stream>>>(dst, x_src, sh, ea, W1, b1, W2, b2, sums, cnt);
    node_kernel<<<(N_NODES*DIMV + 255)/256, 256, 0, stream>>>(x_dst, rw0, rw1, sums, cnt, out);
}

// Round 2
// 454.428 us; speedup vs baseline: 1.8121x; 1.8121x over previous
//
#include <hip/hip_runtime.h>
#include <hip/hip_bf16.h>

#define E_TOT   100000
#define N_NODES 10000
#define DIMV    80
#define HID     64
#define EDIM    32
#define WNUM    2304
#define TE      32

static constexpr float NORMF      = 0.14433756729740643f;  // 1/sqrt(48)
static constexpr float INV_SQRT3F = 0.57735026918962576f;
static constexpr float RS32       = 0.17677669529663687f;  // 1/sqrt(32)
static constexpr float RS16       = 0.25f;                 // 1/sqrt(16)

typedef __attribute__((ext_vector_type(8))) short bf16x8;
typedef __attribute__((ext_vector_type(4))) float f32x4;

static __device__ __forceinline__ ushort f2bf(float v) {
    __hip_bfloat16 h(v);
    return *reinterpret_cast<ushort*>(&h);
}

// Transpose + bf16-convert W2 (HID x WNUM fp32) -> W2T (WNUM x HID bf16)
__global__ __launch_bounds__(256) void prep_w2t(const float* __restrict__ W2,
                                                ushort* __restrict__ W2T) {
    int idx = blockIdx.x * 256 + threadIdx.x;   // over WNUM*HID = 147456
    if (idx >= WNUM * HID) return;
    int j = idx >> 6, t = idx & 63;
    W2T[idx] = f2bf(W2[t * WNUM + j]);
}

// Edge kernel, one block = 32 edges, 4 waves.
//  H = relu(ea@W1+b1) -> bf16 LDS [32][64]
//  A-fragments (H) loaded once to registers; loop 144 column-tiles (16 cols),
//  B direct from L2-resident W2T, 4 MFMA per tile, contract D on the fly
//  into per-lane register partials, one LDS-atomic reduce at the end.
__global__ __launch_bounds__(256) void edge_kernel(
    const int* __restrict__ dst, const float* __restrict__ x_src,
    const float* __restrict__ sh, const float* __restrict__ ea,
    const float* __restrict__ W1, const float* __restrict__ b1,
    const ushort* __restrict__ W2T, const float* __restrict__ b2,
    float* __restrict__ sums, float* __restrict__ cnt)
{
    __shared__ float  sX[TE][DIMV];    // x0 = [0:32), x1[u][m] = [32+3u+m]
    __shared__ float  sSh[TE][4];
    __shared__ float  sXs1[TE][16];    // INV_SQRT3 * sum_m x1[u][m]*sh1[m]
    __shared__ float  cA[TE][32];      // sh0*x0
    __shared__ ushort sHbf[TE][HID];   // H in bf16, row-major [e][t]
    __shared__ float  sB2[WNUM];
    __shared__ float  sMsg[TE][84];    // padded 80->84 (2-way conflict on atomics)
    __shared__ int    sDst[TE];
    __shared__ float  sEa[TE][EDIM];

    const int tid  = threadIdx.x;
    const int lane = tid & 63;
    const int wave = tid >> 6;
    const int e0   = blockIdx.x * TE;

    for (int i = tid; i < TE*DIMV; i += 256) sX[0][i]  = x_src[e0*DIMV + i];
    for (int i = tid; i < TE*EDIM; i += 256) sEa[0][i] = ea[e0*EDIM + i];
    for (int i = tid; i < TE*4;    i += 256) sSh[0][i] = sh[e0*4 + i];
    for (int i = tid; i < WNUM;    i += 256) sB2[i]    = b2[i];
    if (tid < TE) sDst[tid] = dst[e0 + tid];
    __syncthreads();

    // ---- layer 1: H = relu(ea @ W1 + b1), 2048 values, 8/thread
    #pragma unroll
    for (int k = 0; k < (TE*HID)/256; ++k) {
        int idx = tid + k*256;
        int e = idx >> 6, t = idx & 63;
        float h = b1[t];
        #pragma unroll
        for (int i = 0; i < EDIM; ++i) h = fmaf(sEa[e][i], W1[i*HID + t], h);
        sHbf[e][t] = f2bf(fmaxf(h, 0.f));
    }
    for (int i = tid; i < TE*32; i += 256) {
        int e = i >> 5, u = i & 31;
        cA[e][u] = sSh[e][0] * sX[e][u];
    }
    for (int i = tid; i < TE*16; i += 256) {
        int e = i >> 4, u = i & 15;
        sXs1[e][u] = INV_SQRT3F * (sX[e][32+u*3+0]*sSh[e][1] +
                                   sX[e][32+u*3+1]*sSh[e][2] +
                                   sX[e][32+u*3+2]*sSh[e][3]);
    }
    for (int i = tid; i < TE*84; i += 256) sMsg[0][i] = 0.f;
    __syncthreads();

    // ---- A fragments: lane holds A[row=lane&15][k=(lane>>4)*8 ..+8]
    const int c     = lane & 15;
    const int g     = lane >> 4;
    const int rbase = g << 2;
    bf16x8 afrag[2][2];
    #pragma unroll
    for (int rt = 0; rt < 2; ++rt)
        #pragma unroll
        for (int kt = 0; kt < 2; ++kt)
            afrag[rt][kt] = *reinterpret_cast<const bf16x8*>(&sHbf[rt*16 + c][kt*32 + g*8]);

    float pA[8]    = {};   // out0 partial, w = c + 16*(wave&1)
    float sC2[8]   = {};   // sum_u x0*wc
    float sDv[8][3] = {};  // sum_u x1[m]*wd

    // ---- K-loop over 144 column-tiles of 16; wave-strided; no barriers
    for (int t16 = wave; t16 < 144; t16 += 4) {
        const int j0 = t16 << 4;
        const ushort* bp = W2T + ((size_t)(j0 + c) << 6) + g*8;
        bf16x8 bf0 = *reinterpret_cast<const bf16x8*>(bp);
        bf16x8 bf1 = *reinterpret_cast<const bf16x8*>(bp + 32);
        f32x4 acc0 = {0.f, 0.f, 0.f, 0.f};
        f32x4 acc1 = {0.f, 0.f, 0.f, 0.f};
        acc0 = __builtin_amdgcn_mfma_f32_16x16x32_bf16(afrag[0][0], bf0, acc0, 0, 0, 0);
        acc0 = __builtin_amdgcn_mfma_f32_16x16x32_bf16(afrag[0][1], bf1, acc0, 0, 0, 0);
        acc1 = __builtin_amdgcn_mfma_f32_16x16x32_bf16(afrag[1][0], bf0, acc1, 0, 0, 0);
        acc1 = __builtin_amdgcn_mfma_f32_16x16x32_bf16(afrag[1][1], bf1, acc1, 0, 0, 0);
        const float bv = sB2[j0 + c];

        if (t16 < 64) {                       // wa: j = u*32 + w
            const int u = t16 >> 1;
            #pragma unroll
            for (int r = 0; r < 4; ++r) {
                pA[r]   = fmaf(cA[rbase + r][u],      acc0[r] + bv, pA[r]);
                pA[4+r] = fmaf(cA[16 + rbase + r][u], acc1[r] + bv, pA[4+r]);
            }
        } else if (t16 < 96) {                // wc: j-1024 = u*16 + w
            const int u = t16 - 64;
            #pragma unroll
            for (int r = 0; r < 4; ++r) {
                sC2[r]   = fmaf(sX[rbase + r][u],      acc0[r] + bv, sC2[r]);
                sC2[4+r] = fmaf(sX[16 + rbase + r][u], acc1[r] + bv, sC2[4+r]);
            }
        } else if (t16 < 112) {               // wd: j-1536 = u*16 + w
            const int u = t16 - 96;
            #pragma unroll
            for (int r = 0; r < 4; ++r) {
                const float v0 = acc0[r] + bv;
                const float v1 = acc1[r] + bv;
                #pragma unroll
                for (int m = 0; m < 3; ++m) {
                    sDv[r][m]   = fmaf(sX[rbase + r][32 + u*3 + m],      v0, sDv[r][m]);
                    sDv[4+r][m] = fmaf(sX[16 + rbase + r][32 + u*3 + m], v1, sDv[4+r][m]);
                }
            }
        } else {                              // wb: j-1792 = u*32 + w
            const int u = (t16 - 112) >> 1;
            #pragma unroll
            for (int r = 0; r < 4; ++r) {
                pA[r]   = fmaf(sXs1[rbase + r][u],      acc0[r] + bv, pA[r]);
                pA[4+r] = fmaf(sXs1[16 + rbase + r][u], acc1[r] + bv, pA[4+r]);
            }
        }
    }

    // ---- reduce register partials into per-edge msg (LDS atomics)
    const int wcol = c + ((wave & 1) << 4);
    #pragma unroll
    for (int rt = 0; rt < 2; ++rt) {
        #pragma unroll
        for (int r = 0; r < 4; ++r) {
            const int e = rt*16 + rbase + r;
            const int s = rt*4 + r;
            atomicAdd(&sMsg[e][wcol], pA[s]);
            const float s0 = sSh[e][0];
            atomicAdd(&sMsg[e][32 + c*3 + 0], sSh[e][1]*sC2[s] + s0*sDv[s][0]);
            atomicAdd(&sMsg[e][32 + c*3 + 1], sSh[e][2]*sC2[s] + s0*sDv[s][1]);
            atomicAdd(&sMsg[e][32 + c*3 + 2], sSh[e][3]*sC2[s] + s0*sDv[s][2]);
        }
    }
    __syncthreads();

    // ---- scatter to node sums (fold NORM)
    for (int i = tid; i < TE*DIMV; i += 256) {
        int e = i / DIMV, k = i - e*DIMV;
        atomicAdd(&sums[sDst[e]*DIMV + k], NORMF * sMsg[e][k]);
    }
    if (tid < TE) atomicAdd(&cnt[sDst[tid]], 1.0f);
}

// Node kernel: out = residual + sums/max(cnt,1)
__global__ __launch_bounds__(256) void node_kernel(
    const float* __restrict__ x_dst, const float* __restrict__ rw0,
    const float* __restrict__ rw1, const float* __restrict__ sums,
    const float* __restrict__ cnt, float* __restrict__ out)
{
    int gid = blockIdx.x*256 + threadIdx.x;
    if (gid >= N_NODES*DIMV) return;
    int n = gid / DIMV;
    int k = gid - n*DIMV;
    const float* xd = x_dst + n*DIMV;
    float r = 0.f;
    if (k < 32) {
        #pragma unroll
        for (int u = 0; u < 32; ++u) r = fmaf(xd[u], rw0[u*32 + k], r);
        r *= RS32;
    } else {
        int kk = k - 32;
        int w = kk / 3, m = kk - w*3;
        #pragma unroll
        for (int u = 0; u < 16; ++u) r = fmaf(xd[32 + u*3 + m], rw1[u*16 + w], r);
        r *= RS16;
    }
    float cc = cnt[n];
    out[gid] = r + sums[gid] / fmaxf(cc, 1.f);
}

extern "C" void kernel_launch(void* const* d_in, const int* in_sizes, int n_in,
                              void* d_out, int out_size, void* d_ws, size_t ws_size,
                              hipStream_t stream) {
    const int*   dst   = (const int*)  d_in[0];
    const float* x_src = (const float*)d_in[1];
    const float* x_dst = (const float*)d_in[2];
    const float* sh    = (const float*)d_in[3];
    const float* ea    = (const float*)d_in[4];
    const float* W1    = (const float*)d_in[5];
    const float* b1    = (const float*)d_in[6];
    const float* W2    = (const float*)d_in[7];
    const float* b2    = (const float*)d_in[8];
    const float* rw0   = (const float*)d_in[9];
    const float* rw1   = (const float*)d_in[10];
    float* out  = (float*)d_out;

    float*  sums = (float*)d_ws;
    float*  cnt  = sums + (size_t)N_NODES*DIMV;
    ushort* W2T  = (ushort*)((char*)d_ws + (size_t)(N_NODES*DIMV + N_NODES)*sizeof(float));

    hipMemsetAsync(d_ws, 0, (size_t)(N_NODES*DIMV + N_NODES)*sizeof(float), stream);
    prep_w2t<<<(WNUM*HID + 255)/256, 256, 0, stream>>>(W2, W2T);
    edge_kernel<<<E_TOT/TE, 256, 0, stream>>>(dst, x_src, sh, ea, W1, b1, W2T, b2, sums, cnt);
    node_kernel<<<(N_NODES*DIMV + 255)/256, 256, 0, stream>>>(x_dst, rw0, rw1, sums, cnt, out);
}

// Round 5
// 423.544 us; speedup vs baseline: 1.9443x; 1.0729x over previous
//
#include <hip/hip_runtime.h>
#include <hip/hip_bf16.h>

#define E_TOT   100000
#define N_NODES 10000
#define DIMV    80
#define HID     64
#define EDIM    32
#define WNUM    2304
#define TE      32

static constexpr float NORMF      = 0.14433756729740643f;  // 1/sqrt(48)
static constexpr float INV_SQRT3F = 0.57735026918962576f;
static constexpr float RS32       = 0.17677669529663687f;  // 1/sqrt(32)
static constexpr float RS16       = 0.25f;                 // 1/sqrt(16)

typedef __attribute__((ext_vector_type(8))) short bf16x8;
typedef __attribute__((ext_vector_type(4))) float f32x4;

static __device__ __forceinline__ ushort f2bf(float v) {
    __hip_bfloat16 h(v);
    return *reinterpret_cast<ushort*>(&h);
}

// Coalesced transpose + bf16 convert: W2 (HID x WNUM fp32) -> W2T (WNUM x HID bf16)
__global__ __launch_bounds__(256) void prep_w2t(const float* __restrict__ W2,
                                                ushort* __restrict__ W2T) {
    __shared__ float sT[64][65];
    const int j0 = blockIdx.x * 64;
    #pragma unroll
    for (int k = 0; k < 16; ++k) {
        int idx = threadIdx.x + k*256;      // 0..4095
        int t = idx >> 6, j = idx & 63;     // consecutive tid -> consecutive j (coalesced)
        sT[j][t] = W2[t*WNUM + j0 + j];
    }
    __syncthreads();
    #pragma unroll
    for (int k = 0; k < 16; ++k) {
        int idx = threadIdx.x + k*256;
        int j = idx >> 6, t = idx & 63;     // consecutive tid -> consecutive t (coalesced)
        W2T[(size_t)(j0 + j)*64 + t] = f2bf(sT[j][t]);
    }
}

// Edge kernel: block = 32 edges, 4 waves. H=relu(ea@W1+b1) -> bf16.
// Four branch-free region loops over 16-col tiles; B direct from L2-resident
// W2T; b2 folded into accumulator init; per-lane register partials; one
// LDS-atomic reduce; global atomic scatter.
__global__ __launch_bounds__(256, 4) void edge_kernel(
    const int* __restrict__ dst, const float* __restrict__ x_src,
    const float* __restrict__ sh, const float* __restrict__ ea,
    const float* __restrict__ W1, const float* __restrict__ b1,
    const ushort* __restrict__ W2T, const float* __restrict__ b2,
    float* __restrict__ sums, float* __restrict__ cnt)
{
    __shared__ float  sX[TE][81];      // x0=[0:32), x1[u][m]=[32+3u+m]; padded
    __shared__ float  sSh[TE][4];
    __shared__ float  sXs1[TE][17];    // INV_SQRT3 * sum_m x1[u][m]*sh1[m]; padded
    __shared__ float  sEcA[TE][33];    // phase1: ea; phase2: sh0*x0; padded
    __shared__ ushort sHbf[TE][HID];   // H bf16
    __shared__ float  sMsg[TE][84];
    __shared__ int    sDst[TE];

    const int tid  = threadIdx.x;
    const int lane = tid & 63;
    const int wave = tid >> 6;
    const int e0   = blockIdx.x * TE;

    for (int i = tid; i < TE*DIMV; i += 256) { int e = i/80, k = i-e*80; sX[e][k] = x_src[e0*DIMV + i]; }
    for (int i = tid; i < TE*EDIM; i += 256) { int e = i>>5, k = i&31; sEcA[e][k] = ea[e0*EDIM + i]; }
    for (int i = tid; i < TE*4;    i += 256) sSh[0][i] = sh[e0*4 + i];
    if (tid < TE) sDst[tid] = dst[e0 + tid];
    __syncthreads();

    // layer 1: H = relu(ea @ W1 + b1)
    #pragma unroll
    for (int k = 0; k < (TE*HID)/256; ++k) {
        int idx = tid + k*256;
        int e = idx >> 6, t = idx & 63;
        float h = b1[t];
        #pragma unroll
        for (int i = 0; i < EDIM; ++i) h = fmaf(sEcA[e][i], W1[i*HID + t], h);
        sHbf[e][t] = f2bf(fmaxf(h, 0.f));
    }
    __syncthreads();   // layer1 reads of sEcA done before cA overwrite

    for (int i = tid; i < TE*32; i += 256) {
        int e = i >> 5, u = i & 31;
        sEcA[e][u] = sSh[e][0] * sX[e][u];          // cA
    }
    for (int i = tid; i < TE*16; i += 256) {
        int e = i >> 4, u = i & 15;
        sXs1[e][u] = INV_SQRT3F * (sX[e][32+u*3+0]*sSh[e][1] +
                                   sX[e][32+u*3+1]*sSh[e][2] +
                                   sX[e][32+u*3+2]*sSh[e][3]);
    }
    for (int i = tid; i < TE*84; i += 256) sMsg[0][i] = 0.f;
    __syncthreads();

    // A fragments: lane holds H[row=rt*16 + (lane&15)][k=(lane>>4)*8 + kt*32 ..+8]
    const int c     = lane & 15;
    const int g     = lane >> 4;
    const int rbase = g << 2;
    bf16x8 afrag[2][2];
    #pragma unroll
    for (int rt = 0; rt < 2; ++rt)
        #pragma unroll
        for (int kt = 0; kt < 2; ++kt)
            afrag[rt][kt] = *reinterpret_cast<const bf16x8*>(&sHbf[rt*16 + c][kt*32 + g*8]);

    float pA[8]     = {};   // out0 partial, w = c + 16*(wave&1)
    float sC2[8]    = {};
    float sDv[8][3] = {};

    // tile helper: 2 B-loads + b2-splat accumulator init + 4 MFMA
    auto tile_mfma = [&](int t16, f32x4& a0, f32x4& a1) {
        const int j0 = t16 << 4;
        const ushort* bp = W2T + (((size_t)(j0 + c)) << 6) + (g << 3);
        bf16x8 bf0 = *reinterpret_cast<const bf16x8*>(bp);
        bf16x8 bf1 = *reinterpret_cast<const bf16x8*>(bp + 32);
        const float bv = b2[j0 + c];
        a0 = {bv, bv, bv, bv};
        a1 = {bv, bv, bv, bv};
        a0 = __builtin_amdgcn_mfma_f32_16x16x32_bf16(afrag[0][0], bf0, a0, 0, 0, 0);
        a0 = __builtin_amdgcn_mfma_f32_16x16x32_bf16(afrag[0][1], bf1, a0, 0, 0, 0);
        a1 = __builtin_amdgcn_mfma_f32_16x16x32_bf16(afrag[1][0], bf0, a1, 0, 0, 0);
        a1 = __builtin_amdgcn_mfma_f32_16x16x32_bf16(afrag[1][1], bf1, a1, 0, 0, 0);
    };

    // ---- wa: t16 in [0,64), u = t16>>1
    #pragma unroll 2
    for (int k = 0; k < 16; ++k) {
        const int t16 = wave + (k << 2);
        f32x4 a0, a1; tile_mfma(t16, a0, a1);
        const int u = t16 >> 1;
        #pragma unroll
        for (int r = 0; r < 4; ++r) {
            pA[r]   = fmaf(sEcA[rbase + r][u],      a0[r], pA[r]);
            pA[4+r] = fmaf(sEcA[16 + rbase + r][u], a1[r], pA[4+r]);
        }
    }
    // ---- wc: t16 in [64,96), u = t16-64
    #pragma unroll 2
    for (int k = 0; k < 8; ++k) {
        const int t16 = 64 + wave + (k << 2);
        f32x4 a0, a1; tile_mfma(t16, a0, a1);
        const int u = t16 - 64;
        #pragma unroll
        for (int r = 0; r < 4; ++r) {
            sC2[r]   = fmaf(sX[rbase + r][u],      a0[r], sC2[r]);
            sC2[4+r] = fmaf(sX[16 + rbase + r][u], a1[r], sC2[4+r]);
        }
    }
    // ---- wd: t16 in [96,112), u = t16-96
    #pragma unroll
    for (int k = 0; k < 4; ++k) {
        const int t16 = 96 + wave + (k << 2);
        f32x4 a0, a1; tile_mfma(t16, a0, a1);
        const int u = t16 - 96;
        #pragma unroll
        for (int r = 0; r < 4; ++r) {
            #pragma unroll
            for (int m = 0; m < 3; ++m) {
                sDv[r][m]   = fmaf(sX[rbase + r][32 + u*3 + m],      a0[r], sDv[r][m]);
                sDv[4+r][m] = fmaf(sX[16 + rbase + r][32 + u*3 + m], a1[r], sDv[4+r][m]);
            }
        }
    }
    // ---- wb: t16 in [112,144), u = (t16-112)>>1
    #pragma unroll 2
    for (int k = 0; k < 8; ++k) {
        const int t16 = 112 + wave + (k << 2);
        f32x4 a0, a1; tile_mfma(t16, a0, a1);
        const int u = (t16 - 112) >> 1;
        #pragma unroll
        for (int r = 0; r < 4; ++r) {
            pA[r]   = fmaf(sXs1[rbase + r][u],      a0[r], pA[r]);
            pA[4+r] = fmaf(sXs1[16 + rbase + r][u], a1[r], pA[4+r]);
        }
    }

    // ---- reduce partials into per-edge msg (LDS atomics)
    const int wcol = c + ((wave & 1) << 4);
    #pragma unroll
    for (int rt = 0; rt < 2; ++rt) {
        #pragma unroll
        for (int r = 0; r < 4; ++r) {
            const int e = rt*16 + rbase + r;
            const int s = rt*4 + r;
            atomicAdd(&sMsg[e][wcol], pA[s]);
            const float s0 = sSh[e][0];
            atomicAdd(&sMsg[e][32 + c*3 + 0], sSh[e][1]*sC2[s] + s0*sDv[s][0]);
            atomicAdd(&sMsg[e][32 + c*3 + 1], sSh[e][2]*sC2[s] + s0*sDv[s][1]);
            atomicAdd(&sMsg[e][32 + c*3 + 2], sSh[e][3]*sC2[s] + s0*sDv[s][2]);
        }
    }
    __syncthreads();

    // ---- scatter to node sums (fold NORM)
    for (int i = tid; i < TE*DIMV; i += 256) {
        int e = i / DIMV, k = i - e*DIMV;
        atomicAdd(&sums[sDst[e]*DIMV + k], NORMF * sMsg[e][k]);
    }
    if (tid < TE) atomicAdd(&cnt[sDst[tid]], 1.0f);
}

// Node kernel: out = residual + sums/max(cnt,1)
__global__ __launch_bounds__(256) void node_kernel(
    const float* __restrict__ x_dst, const float* __restrict__ rw0,
    const float* __restrict__ rw1, const float* __restrict__ sums,
    const float* __restrict__ cnt, float* __restrict__ out)
{
    int gid = blockIdx.x*256 + threadIdx.x;
    if (gid >= N_NODES*DIMV) return;
    int n = gid / DIMV;
    int k = gid - n*DIMV;
    const float* xd = x_dst + n*DIMV;
    float r = 0.f;
    if (k < 32) {
        #pragma unroll
        for (int u = 0; u < 32; ++u) r = fmaf(xd[u], rw0[u*32 + k], r);
        r *= RS32;
    } else {
        int kk = k - 32;
        int w = kk / 3, m = kk - w*3;
        #pragma unroll
        for (int u = 0; u < 16; ++u) r = fmaf(xd[32 + u*3 + m], rw1[u*16 + w], r);
        r *= RS16;
    }
    float cc = cnt[n];
    out[gid] = r + sums[gid] / fmaxf(cc, 1.f);
}

extern "C" void kernel_launch(void* const* d_in, const int* in_sizes, int n_in,
                              void* d_out, int out_size, void* d_ws, size_t ws_size,
                              hipStream_t stream) {
    const int*   dst   = (const int*)  d_in[0];
    const float* x_src = (const float*)d_in[1];
    const float* x_dst = (const float*)d_in[2];
    const float* sh    = (const float*)d_in[3];
    const float* ea    = (const float*)d_in[4];
    const float* W1    = (const float*)d_in[5];
    const float* b1    = (const float*)d_in[6];
    const float* W2    = (const float*)d_in[7];
    const float* b2    = (const float*)d_in[8];
    const float* rw0   = (const float*)d_in[9];
    const float* rw1   = (const float*)d_in[10];
    float* out  = (float*)d_out;

    float*  sums = (float*)d_ws;
    float*  cnt  = sums + (size_t)N_NODES*DIMV;
    ushort* W2T  = (ushort*)((char*)d_ws + (size_t)(N_NODES*DIMV + N_NODES)*sizeof(float));

    hipMemsetAsync(d_ws, 0, (size_t)(N_NODES*DIMV + N_NODES)*sizeof(float), stream);
    prep_w2t<<<WNUM/64, 256, 0, stream>>>(W2, W2T);
    edge_kernel<<<E_TOT/TE, 256, 0, stream>>>(dst, x_src, sh, ea, W1, b1, W2T, b2, sums, cnt);
    node_kernel<<<(N_NODES*DIMV + 255)/256, 256, 0, stream>>>(x_dst, rw0, rw1, sums, cnt, out);
}